// Round 1
// baseline (699.529 us; speedup 1.0000x reference)
//
#include <hip/hip_runtime.h>

#define NCOL 64
#define KDIM 128

// ---------------- K2: degree computation ----------------
__global__ void deg_kernel(const int* __restrict__ src, const int* __restrict__ dst,
                           float* __restrict__ outdeg, float* __restrict__ indeg, int E) {
    int i = blockIdx.x * blockDim.x + threadIdx.x;
    int stride = gridDim.x * blockDim.x;
    for (int e = i; e < E; e += stride) {
        unsafeAtomicAdd(&outdeg[src[e]], 1.0f);
        unsafeAtomicAdd(&indeg[dst[e]], 1.0f);
    }
}

// ---------------- K3: dual matvec: h = (feat*norm_src)@W ; res = relu(feat@RW + rb) ----------------
// Block: 256 threads = 4 waves. Each wave: 8 nodes, lane = out column.
// W staged in LDS transposed [col][k] with 16B-chunk XOR swizzle (chunk ^= col&7)
// so ds_read_b128 across 64 lanes is conflict-free.
__global__ __launch_bounds__(256) void matmul_kernel(
    const float* __restrict__ feat, const float* __restrict__ W,
    const float* __restrict__ RW, const float* __restrict__ res_b,
    const float* __restrict__ outdeg,
    float* __restrict__ h, float* __restrict__ res_out, int N) {
    __shared__ float Wt[NCOL][KDIM];
    __shared__ float RWt[NCOL][KDIM];
    int tid = threadIdx.x;
    for (int idx = tid; idx < KDIM * NCOL; idx += 256) {
        int k = idx >> 6, c = idx & 63;
        int a = (((k >> 2) ^ (c & 7)) << 2) | (k & 3);
        Wt[c][a] = W[idx];
        RWt[c][a] = RW[idx];
    }
    __syncthreads();

    int c = tid & 63;
    int w = tid >> 6;
    int base = blockIdx.x * 32 + w * 8;

    int nidx[8];
#pragma unroll
    for (int u = 0; u < 8; ++u) {
        int n = base + u;
        nidx[u] = n < N ? n : 0;   // clamp for safe loads; stores guarded below
    }

    float hacc[8], racc[8];
#pragma unroll
    for (int u = 0; u < 8; ++u) { hacc[u] = 0.0f; racc[u] = 0.0f; }

    const int swz = (c & 7) << 2;
#pragma unroll 8
    for (int k4 = 0; k4 < KDIM / 4; ++k4) {
        float4 wv = *(const float4*)&Wt[c][(k4 << 2) ^ swz];
        float4 rv = *(const float4*)&RWt[c][(k4 << 2) ^ swz];
#pragma unroll
        for (int u = 0; u < 8; ++u) {
            float4 f = *(const float4*)&feat[(size_t)nidx[u] * KDIM + (k4 << 2)];
            hacc[u] += f.x * wv.x + f.y * wv.y + f.z * wv.z + f.w * wv.w;
            racc[u] += f.x * rv.x + f.y * rv.y + f.z * rv.z + f.w * rv.w;
        }
    }

    float rb = res_b[c];
#pragma unroll
    for (int u = 0; u < 8; ++u) {
        int n = base + u;
        if (n < N) {
            float ns = rsqrtf(fmaxf(outdeg[n], 1.0f));
            h[(size_t)n * NCOL + c] = hacc[u] * ns;
            float r = racc[u] + rb;
            res_out[(size_t)n * NCOL + c] = r > 0.0f ? r : 0.0f;
        }
    }
}

// ---------------- K4: edge scatter: agg[dst] += h[src] ----------------
// One wave per edge; lane = column. 256B coalesced read + 64 contiguous atomics.
__global__ __launch_bounds__(256) void scatter_kernel(
    const int* __restrict__ src, const int* __restrict__ dst,
    const float* __restrict__ h, float* __restrict__ agg, int E) {
    int lane = threadIdx.x & 63;
    int wave = (int)((blockIdx.x * blockDim.x + threadIdx.x) >> 6);
    int nwaves = (gridDim.x * blockDim.x) >> 6;
    for (int e = wave; e < E; e += nwaves) {
        int s = src[e];
        int d = dst[e];
        float v = h[(size_t)s * NCOL + lane];
        unsafeAtomicAdd(&agg[(size_t)d * NCOL + lane], v);
    }
}

// ---------------- K5: finalize: y = relu(agg*norm_dst + b) + res ; BN partial sums ----------------
__global__ __launch_bounds__(256) void finalize_kernel(
    const float* __restrict__ agg, const float* __restrict__ indeg,
    const float* __restrict__ b, float* __restrict__ y,
    float* __restrict__ stats, int N) {
    __shared__ float red[512];
    int tid = threadIdx.x;
    int c = tid & 63;
    int w = tid >> 6;
    int nw = gridDim.x * 4;
    float bc = b[c];
    float lsum = 0.0f, lsq = 0.0f;
    for (int n = blockIdx.x * 4 + w; n < N; n += nw) {
        float nd = rsqrtf(fmaxf(indeg[n], 1.0f));
        float conv = agg[(size_t)n * NCOL + c] * nd + bc;
        conv = conv > 0.0f ? conv : 0.0f;
        float v = conv + y[(size_t)n * NCOL + c];
        y[(size_t)n * NCOL + c] = v;
        lsum += v;
        lsq += v * v;
    }
    red[tid] = lsum;
    red[256 + tid] = lsq;
    __syncthreads();
    if (tid < 64) {
        float s = red[tid] + red[tid + 64] + red[tid + 128] + red[tid + 192];
        float q = red[256 + tid] + red[256 + tid + 64] + red[256 + tid + 128] + red[256 + tid + 192];
        unsafeAtomicAdd(&stats[tid], s);
        unsafeAtomicAdd(&stats[64 + tid], q);
    }
}

// ---------------- K6: BN scale/shift ----------------
__global__ void bnparam_kernel(const float* __restrict__ gamma, const float* __restrict__ beta,
                               float* __restrict__ stats, float invN) {
    int c = threadIdx.x;
    float mean = stats[c] * invN;
    float var = stats[64 + c] * invN - mean * mean;
    float s = gamma[c] * rsqrtf(var + 1e-5f);
    stats[128 + c] = s;
    stats[192 + c] = beta[c] - mean * s;
}

// ---------------- K7: BN apply (in place, float4) ----------------
__global__ __launch_bounds__(256) void apply_kernel(float* __restrict__ y,
                                                    const float* __restrict__ stats, int total4) {
    int i = blockIdx.x * blockDim.x + threadIdx.x;
    int stride = gridDim.x * blockDim.x;
    float4* y4 = (float4*)y;
    for (; i < total4; i += stride) {
        float4 v = y4[i];
        int cbase = (i & 15) << 2;
        float4 s = *(const float4*)&stats[128 + cbase];
        float4 t = *(const float4*)&stats[192 + cbase];
        v.x = v.x * s.x + t.x;
        v.y = v.y * s.y + t.y;
        v.z = v.z * s.z + t.z;
        v.w = v.w * s.w + t.w;
        y4[i] = v;
    }
}

extern "C" void kernel_launch(void* const* d_in, const int* in_sizes, int n_in,
                              void* d_out, int out_size, void* d_ws, size_t ws_size,
                              hipStream_t stream) {
    const float* feat  = (const float*)d_in[0];
    const int*   src   = (const int*)d_in[1];
    const int*   dst   = (const int*)d_in[2];
    const float* W     = (const float*)d_in[3];
    const float* b     = (const float*)d_in[4];
    const float* RW    = (const float*)d_in[5];
    const float* rb    = (const float*)d_in[6];
    const float* gamma = (const float*)d_in[7];
    const float* beta  = (const float*)d_in[8];

    int N = in_sizes[0] / KDIM;
    int E = in_sizes[1];
    float* out = (float*)d_out;

    float* ws     = (float*)d_ws;
    float* h      = ws;                          // N*64
    float* agg    = h + (size_t)N * NCOL;        // N*64
    float* outdeg = agg + (size_t)N * NCOL;      // N
    float* indeg  = outdeg + N;                  // N
    float* stats  = indeg + N;                   // 256

    // zero agg .. stats (contiguous)
    size_t zero_bytes = ((size_t)N * NCOL + 2 * (size_t)N + 256) * sizeof(float);
    hipMemsetAsync(agg, 0, zero_bytes, stream);

    deg_kernel<<<1024, 256, 0, stream>>>(src, dst, outdeg, indeg, E);
    matmul_kernel<<<(N + 31) / 32, 256, 0, stream>>>(feat, W, RW, rb, outdeg, h, out, N);
    scatter_kernel<<<4096, 256, 0, stream>>>(src, dst, h, agg, E);
    finalize_kernel<<<1024, 256, 0, stream>>>(agg, indeg, b, out, stats, N);
    bnparam_kernel<<<1, 64, 0, stream>>>(gamma, beta, stats, 1.0f / (float)N);
    apply_kernel<<<2048, 256, 0, stream>>>(out, stats, (N * NCOL) / 4);
}